// Round 3
// baseline (205.080 us; speedup 1.0000x reference)
//
#include <hip/hip_runtime.h>

#define POOLP 7
#define NB 8
#define IH 64
#define IW 64
#define NC 1024
#define NR 32
#define NWORK (NR * POOLP)   // 224 (r,py) jobs per batch

typedef float vfloat4 __attribute__((ext_vector_type(4)));

// Schedule: the 224 (r,py) jobs sorted by first image row touched (Y0).
// ROI geometry is hardcoded here ONLY as a scheduling hint — the kernel
// still reads rois[] from memory for all arithmetic; a different roi set
// would still be computed correctly, just without row-locality.
struct Sched { unsigned char rp[NWORK]; };

constexpr Sched make_sched() {
    int ry[NR] = {0,0,0,0,16,16,16,16,32,32,32,32,48,48,48,48,
                  0,0,32,32,
                  0,0,0,21,21,21,42,42,42,
                  0,8,16};
    int rh[NR] = {16,16,16,16,16,16,16,16,16,16,16,16,16,16,16,16,
                  32,32,32,32,
                  21,21,21,21,21,21,21,21,21,
                  64,48,32};
    Sched s{};
    int key[NWORK] = {};
    for (int r = 0; r < NR; ++r) {
        for (int py = 0; py < POOLP; ++py) {
            // cy = (py+0.5)*h/7 - 0.5 = ((2py+1)h - 7)/14 ; >= 0 for all rois
            int num = (2 * py + 1) * rh[r] - POOLP;
            int y0 = num / 14;               // floor(cy)
            int idx = r * POOLP + py;
            key[idx] = ry[r] + y0;           // first image row touched
            s.rp[idx] = (unsigned char)((r << 3) | py);
        }
    }
    for (int i = 1; i < NWORK; ++i) {        // stable insertion sort by key
        int k = key[i]; unsigned char v = s.rp[i];
        int j = i - 1;
        while (j >= 0 && key[j] > k) { key[j+1] = key[j]; s.rp[j+1] = s.rp[j]; --j; }
        key[j+1] = k; s.rp[j+1] = v;
    }
    return s;
}

__device__ __constant__ Sched d_sched = make_sched();

// One block per (job o, b); 256 threads each own one float4 of the 1024
// channels and loop over the 7 px positions.
//
// Mechanism under test (R3): bounded-window L2 reuse.
//  - jobs row-sorted (d_sched) so neighbors touch neighboring image rows
//  - 64 KB dummy LDS caps residency at 2 blocks/CU -> ~64 resident jobs
//    per XCD ~= 18-row window ~= 4 MB touched pixels ~= XCD L2 size
//  - img loads ALLOCATING so the window is cached (R1 showed allocating
//    without the window loses; NT never hits)
//  - stores stay NT: keep L2 clean for the image
__global__ __launch_bounds__(256) void roi_align_kernel(
    const float* __restrict__ img,
    const int* __restrict__ rois,
    float* __restrict__ out)
{
    // Residency throttle: 64 KB LDS -> 2 blocks/CU. Never-true block-uniform
    // branch keeps the allocation live without runtime cost.
    __shared__ float lds_throttle[16384];
    if ((int)blockIdx.x < 0) {
        lds_throttle[threadIdx.x] = (float)threadIdx.x;
        out[0] = lds_throttle[threadIdx.x];
    }

    int b = blockIdx.x & 7;          // batch -> XCD (round-robin matches % 8)
    int o = blockIdx.x >> 3;         // scheduled job index, 0..223
    int rp = d_sched.rp[o];
    int r  = rp >> 3;                // 0..31
    int py = rp & 7;                 // 0..6

    int rx = rois[r * 4 + 0];
    int ry = rois[r * 4 + 1];
    int rw = rois[r * 4 + 2];
    int rh = rois[r * 4 + 3];

    // Replicate reference fp32 arithmetic exactly:
    // coord = (out + 0.5) * (size / 7) - 0.5
    float sx = (float)rw / (float)POOLP;
    float sy = (float)rh / (float)POOLP;

    float cy = ((float)py + 0.5f) * sy - 0.5f;
    float fy = floorf(cy);
    int y0 = max((int)fy, 0);
    int y1 = min(max((int)ceilf(cy), 0), rh - 1);
    float wy = cy - fy;
    int Y0 = ry + y0, Y1 = ry + y1;

    const float* row0 = img + (((size_t)b * IH + Y0) * IW) * NC;
    const float* row1 = img + (((size_t)b * IH + Y1) * IW) * NC;

    int c4 = threadIdx.x;  // float4 index within channels, 0..255

    // Output base for (r, b, py): (((r*NB + b)*POOLP + py)*POOLP + px)*NC + c
    float* obase = out + ((((size_t)r * NB + b) * POOLP + py) * POOLP) * NC;

#pragma unroll
    for (int px = 0; px < POOLP; ++px) {
        float cx = ((float)px + 0.5f) * sx - 0.5f;
        float fx = floorf(cx);
        int x0 = max((int)fx, 0);
        int x1 = min(max((int)ceilf(cx), 0), rw - 1);
        float wx = cx - fx;
        int X0 = rx + x0, X1 = rx + x1;

        const vfloat4* i00 = (const vfloat4*)(row0 + (size_t)X0 * NC) + c4;
        const vfloat4* i01 = (const vfloat4*)(row0 + (size_t)X1 * NC) + c4;
        const vfloat4* i10 = (const vfloat4*)(row1 + (size_t)X0 * NC) + c4;
        const vfloat4* i11 = (const vfloat4*)(row1 + (size_t)X1 * NC) + c4;

        vfloat4 v00 = *i00;   // allocating: duplicates L1-hit, window L2-hits
        vfloat4 v01 = *i01;
        vfloat4 v10 = *i10;
        vfloat4 v11 = *i11;

        vfloat4 top = v00 + (v01 - v00) * wx;
        vfloat4 bot = v10 + (v11 - v10) * wx;
        vfloat4 res = top + (bot - top) * wy;

        __builtin_nontemporal_store(res, (vfloat4*)(obase + (size_t)px * NC) + c4);
    }
}

extern "C" void kernel_launch(void* const* d_in, const int* in_sizes, int n_in,
                              void* d_out, int out_size, void* d_ws, size_t ws_size,
                              hipStream_t stream) {
    const float* img = (const float*)d_in[0];
    const int* rois = (const int*)d_in[1];
    float* out = (float*)d_out;

    int nblocks = NWORK * NB;  // 1792 blocks, each does 7 px positions
    roi_align_kernel<<<nblocks, 256, 0, stream>>>(img, rois, out);
}

// Round 4
// 199.154 us; speedup vs baseline: 1.0298x; 1.0298x over previous
//
#include <hip/hip_runtime.h>

#define POOLP 7
#define NB 8
#define IH 64
#define IW 64
#define NC 1024
#define NR 32

typedef float vfloat4 __attribute__((ext_vector_type(4)));

// One block per (r, b, py); 256 threads each own one float4 of the 1024
// channels and loop over the 7 px positions.
//
// All image reads are nontemporal. Session evidence (R1/R2/R3):
//  - allocating loads alone:          +9 us  (L2 thrash, zero net reuse)
//  - explicit same-addr dedup (21s):  neutral (MSHRs already merge in-flight dups)
//  - row-sorted schedule + 2 blk/CU
//    residency throttle + allocating: +5 us  (window reuse < thrash cost)
// => NT streaming is the winning regime. Kernel ~40 us at ~5.3 TB/s effective
//    (84% of 6.29 TB/s copy ceiling) on ~87%-compulsory traffic
//    (162 MB fetch + 51 MB store). Stores NT too (51 MB write-once stream).
__global__ __launch_bounds__(256) void roi_align_kernel(
    const float* __restrict__ img,
    const int* __restrict__ rois,
    float* __restrict__ out)
{
    int b = blockIdx.x & 7;          // batch -> XCD (round-robin matches % 8)
    int rest = blockIdx.x >> 3;      // 0..223
    int py = rest % POOLP;
    int r  = rest / POOLP;           // 0..31

    int rx = rois[r * 4 + 0];
    int ry = rois[r * 4 + 1];
    int rw = rois[r * 4 + 2];
    int rh = rois[r * 4 + 3];

    // Replicate reference fp32 arithmetic exactly:
    // coord = (out + 0.5) * (size / 7) - 0.5
    float sx = (float)rw / (float)POOLP;
    float sy = (float)rh / (float)POOLP;

    float cy = ((float)py + 0.5f) * sy - 0.5f;
    float fy = floorf(cy);
    int y0 = max((int)fy, 0);
    int y1 = min(max((int)ceilf(cy), 0), rh - 1);
    float wy = cy - fy;
    int Y0 = ry + y0, Y1 = ry + y1;

    const float* row0 = img + (((size_t)b * IH + Y0) * IW) * NC;
    const float* row1 = img + (((size_t)b * IH + Y1) * IW) * NC;

    int c4 = threadIdx.x;  // float4 index within channels, 0..255

    // Output base for (r, b, py): (((r*NB + b)*POOLP + py)*POOLP + px)*NC + c
    float* obase = out + ((((size_t)r * NB + b) * POOLP + py) * POOLP) * NC;

#pragma unroll
    for (int px = 0; px < POOLP; ++px) {
        float cx = ((float)px + 0.5f) * sx - 0.5f;
        float fx = floorf(cx);
        int x0 = max((int)fx, 0);
        int x1 = min(max((int)ceilf(cx), 0), rw - 1);
        float wx = cx - fx;
        int X0 = rx + x0, X1 = rx + x1;

        const vfloat4* i00 = (const vfloat4*)(row0 + (size_t)X0 * NC) + c4;
        const vfloat4* i01 = (const vfloat4*)(row0 + (size_t)X1 * NC) + c4;
        const vfloat4* i10 = (const vfloat4*)(row1 + (size_t)X0 * NC) + c4;
        const vfloat4* i11 = (const vfloat4*)(row1 + (size_t)X1 * NC) + c4;

        vfloat4 v00 = __builtin_nontemporal_load(i00);
        vfloat4 v01 = __builtin_nontemporal_load(i01);
        vfloat4 v10 = __builtin_nontemporal_load(i10);
        vfloat4 v11 = __builtin_nontemporal_load(i11);

        vfloat4 top = v00 + (v01 - v00) * wx;
        vfloat4 bot = v10 + (v11 - v10) * wx;
        vfloat4 res = top + (bot - top) * wy;

        __builtin_nontemporal_store(res, (vfloat4*)(obase + (size_t)px * NC) + c4);
    }
}

extern "C" void kernel_launch(void* const* d_in, const int* in_sizes, int n_in,
                              void* d_out, int out_size, void* d_ws, size_t ws_size,
                              hipStream_t stream) {
    const float* img = (const float*)d_in[0];
    const int* rois = (const int*)d_in[1];
    float* out = (float*)d_out;

    int nblocks = NR * NB * POOLP;  // 1792 blocks, each does 7 px positions
    roi_align_kernel<<<nblocks, 256, 0, stream>>>(img, rois, out);
}